// Round 1
// 356.998 us; speedup vs baseline: 1.0642x; 1.0642x over previous
//
#include <hip/hip_runtime.h>
#include <math.h>

#define NB 8
#define NS 2048
#define ND 512
#define NHH 8
#define NDH 64

typedef __attribute__((ext_vector_type(4))) float f32x4;
typedef __attribute__((ext_vector_type(8))) short bf16x8;
typedef unsigned short ush;

__device__ inline ush f2bf_rne(float f) {
    unsigned u = __float_as_uint(f);
    unsigned r = u + 0x7FFFu + ((u >> 16) & 1u);
    return (ush)(r >> 16);
}
__device__ inline float bf2f(ush h) { return __uint_as_float(((unsigned)h) << 16); }

// packed f32x2 -> bf16x2 (RNE), single VALU instruction
__device__ inline unsigned cvt_pk_bf16(float lo, float hi) {
    unsigned r;
    asm("v_cvt_pk_bf16_f32 %0, %1, %2" : "=v"(r) : "v"(lo), "v"(hi));
    return r;
}

#if defined(__has_builtin)
#if __has_builtin(__builtin_amdgcn_exp2f)
#define EXP2F(x) __builtin_amdgcn_exp2f(x)
#else
#define EXP2F(x) exp2f(x)
#endif
#else
#define EXP2F(x) exp2f(x)
#endif

// async global->LDS, 16B per lane (global_load_lds_dwordx4)
#define GLL16(gp, lp) __builtin_amdgcn_global_load_lds( \
    (const __attribute__((address_space(1))) unsigned int*)(gp), \
    (__attribute__((address_space(3))) unsigned int*)(lp), 16, 0, 0)

// ---------------------------------------------------------------------------
// Kernel 0: weight conversion. y<3: Wq/Wk/Wv -> bf16. y==3: Wo -> hi/lo bf16.
// ---------------------------------------------------------------------------
__global__ __launch_bounds__(256) void conv_w_kernel(
    const float* __restrict__ Wq, const float* __restrict__ Wk,
    const float* __restrict__ Wv, const float* __restrict__ Wo,
    ush* __restrict__ wbf, ush* __restrict__ wo_hi, ush* __restrict__ wo_lo)
{
    const int y = blockIdx.y;
    const int i = (blockIdx.x * 256 + threadIdx.x) * 4;
    if (y < 3) {
        const float* src = (y == 0) ? Wq : (y == 1) ? Wk : Wv;
        const float4 v = *(const float4*)&src[i];
        ushort4 o;
        o.x = f2bf_rne(v.x); o.y = f2bf_rne(v.y);
        o.z = f2bf_rne(v.z); o.w = f2bf_rne(v.w);
        *(ushort4*)&wbf[y * 262144 + i] = o;
    } else {
        const float4 v = *(const float4*)&Wo[i];
        ushort4 hi, lo;
        hi.x = f2bf_rne(v.x); lo.x = f2bf_rne(v.x - bf2f(hi.x));
        hi.y = f2bf_rne(v.y); lo.y = f2bf_rne(v.y - bf2f(hi.y));
        hi.z = f2bf_rne(v.z); lo.z = f2bf_rne(v.z - bf2f(hi.z));
        hi.w = f2bf_rne(v.w); lo.w = f2bf_rne(v.w - bf2f(hi.w));
        *(ushort4*)&wo_hi[i] = hi;
        *(ushort4*)&wo_lo[i] = lo;
    }
}

// ---------------------------------------------------------------------------
// Kernel 1: QKV projections via bf16 MFMA. C = X @ W^T + b.
// 128x128 tile, BK=32, 4 waves (2x2 of 64x64), 16x16x32 MFMA.
// LDS layout (per 16-row chunk): slot i (16B) holds row (i>>2), k-group
// g = (i&3) ^ s(i>>2), s(r) = (r + (r>>2)) & 3  -> staging writes and
// ds_read_b128 frag reads both hit the quarter-wave bank floor.
// A (x fp32) converted in-staging; B (weights bf16) staged via GLL16.
// Epilogue: z=0 Q (scaled 0.125*log2e, B,H,S,DH bf16); z=1 K (same, scale 1);
// z=2 V stored TRANSPOSED (B,H,DH,S) via packed ushort4 (r-consecutive rows).
// ---------------------------------------------------------------------------
__global__ __launch_bounds__(256) void qkv_gemm_kernel(
    const float* __restrict__ xq, const float* __restrict__ xk, const float* __restrict__ xv,
    const ush* __restrict__ wbf,
    const float* __restrict__ bq, const float* __restrict__ bk, const float* __restrict__ bv,
    ush* __restrict__ Qb, ush* __restrict__ Kb, ush* __restrict__ VT)
{
    __shared__ ush As[4096];   // 8 chunks x 512 shorts = 8 KB
    __shared__ ush Bs[4096];

    const int z = blockIdx.z;
    const float* X    = (z == 0) ? xq : (z == 1) ? xk : xv;
    const ush*   W    = wbf + z * 262144;
    const float* bias = (z == 0) ? bq : (z == 1) ? bk : bv;

    const int t = threadIdx.x;
    const int w = t >> 6, l = t & 63;
    const int l15 = l & 15, g = l >> 4;
    const int m0 = blockIdx.x * 128, n0 = blockIdx.y * 128;
    const int wm = (w & 1) << 6, wn = (w >> 1) << 6;

    const int srow = l >> 2;                                   // row within chunk
    const int sg   = (l & 3) ^ ((srow + (srow >> 2)) & 3);     // staged k-group
    const int fsw  = (g ^ ((l15 + (l15 >> 2)) & 3)) << 3;      // frag-read swizzle (shorts)
    const int c0   = w * 2;                                    // this wave's chunks

    f32x4 acc[4][4];
    #pragma unroll
    for (int i = 0; i < 4; ++i)
        #pragma unroll
        for (int j = 0; j < 4; ++j) acc[i][j] = (f32x4)(0.0f);

    for (int kt = 0; kt < 512; kt += 32) {
        // A source loads (fp32), before barrier (no LDS hazard)
        const size_t ar0 = (size_t)(m0 + c0 * 16 + srow) * 512 + kt + sg * 8;
        const size_t ar1 = (size_t)(m0 + (c0 + 1) * 16 + srow) * 512 + kt + sg * 8;
        const float4 a0 = *(const float4*)&X[ar0];
        const float4 a1 = *(const float4*)&X[ar0 + 4];
        const float4 a2 = *(const float4*)&X[ar1];
        const float4 a3 = *(const float4*)&X[ar1 + 4];

        __syncthreads();   // previous iteration's frag reads complete

        // B: async bf16 staging
        GLL16(&W[(size_t)(n0 + c0 * 16 + srow) * 512 + kt + sg * 8], &Bs[c0 * 512 + l * 8]);
        GLL16(&W[(size_t)(n0 + (c0 + 1) * 16 + srow) * 512 + kt + sg * 8], &Bs[(c0 + 1) * 512 + l * 8]);

        // A: convert + ds_write_b128
        uint4 u0, u1;
        u0.x = (unsigned)f2bf_rne(a0.x) | ((unsigned)f2bf_rne(a0.y) << 16);
        u0.y = (unsigned)f2bf_rne(a0.z) | ((unsigned)f2bf_rne(a0.w) << 16);
        u0.z = (unsigned)f2bf_rne(a1.x) | ((unsigned)f2bf_rne(a1.y) << 16);
        u0.w = (unsigned)f2bf_rne(a1.z) | ((unsigned)f2bf_rne(a1.w) << 16);
        u1.x = (unsigned)f2bf_rne(a2.x) | ((unsigned)f2bf_rne(a2.y) << 16);
        u1.y = (unsigned)f2bf_rne(a2.z) | ((unsigned)f2bf_rne(a2.w) << 16);
        u1.z = (unsigned)f2bf_rne(a3.x) | ((unsigned)f2bf_rne(a3.y) << 16);
        u1.w = (unsigned)f2bf_rne(a3.z) | ((unsigned)f2bf_rne(a3.w) << 16);
        *(uint4*)&As[c0 * 512 + l * 8] = u0;
        *(uint4*)&As[(c0 + 1) * 512 + l * 8] = u1;

        __syncthreads();   // staged tile visible (compiler drains vmcnt+lgkm)

        bf16x8 af[4], bfr[4];
        #pragma unroll
        for (int mi = 0; mi < 4; ++mi)
            af[mi] = *(const bf16x8*)&As[(((w & 1) << 2) + mi) * 512 + l15 * 32 + fsw];
        #pragma unroll
        for (int ni = 0; ni < 4; ++ni)
            bfr[ni] = *(const bf16x8*)&Bs[(((w >> 1) << 2) + ni) * 512 + l15 * 32 + fsw];
        #pragma unroll
        for (int mi = 0; mi < 4; ++mi)
            #pragma unroll
            for (int ni = 0; ni < 4; ++ni)
                acc[mi][ni] = __builtin_amdgcn_mfma_f32_16x16x32_bf16(af[mi], bfr[ni], acc[mi][ni], 0, 0, 0);
    }

    const float qscale = (z == 0) ? 0.18033688011112042f : 1.0f;   // 0.125*log2(e)
    float bnv[4];
    #pragma unroll
    for (int ni = 0; ni < 4; ++ni) bnv[ni] = bias[n0 + wn + ni * 16 + l15];

    if (z < 2) {
        ush* O = (z == 0) ? Qb : Kb;
        #pragma unroll
        for (int mi = 0; mi < 4; ++mi) {
            #pragma unroll
            for (int ni = 0; ni < 4; ++ni) {
                const int n = n0 + wn + ni * 16 + l15;
                const int hh = n >> 6, dh = n & 63;
                #pragma unroll
                for (int r = 0; r < 4; ++r) {
                    const int m = m0 + wm + mi * 16 + (g << 2) + r;
                    const int bi = m >> 11, s = m & (NS - 1);
                    O[((size_t)(bi * 8 + hh) * 2048 + s) * 64 + dh] =
                        f2bf_rne((acc[mi][ni][r] + bnv[ni]) * qscale);
                }
            }
        }
    } else {
        #pragma unroll
        for (int mi = 0; mi < 4; ++mi) {
            #pragma unroll
            for (int ni = 0; ni < 4; ++ni) {
                const int n = n0 + wn + ni * 16 + l15;
                const int hh = n >> 6, dh = n & 63;
                const int mb = m0 + wm + mi * 16 + (g << 2);
                const int bi = mb >> 11, s = mb & (NS - 1);
                ushort4 pk;
                pk.x = f2bf_rne(acc[mi][ni][0] + bnv[ni]);
                pk.y = f2bf_rne(acc[mi][ni][1] + bnv[ni]);
                pk.z = f2bf_rne(acc[mi][ni][2] + bnv[ni]);
                pk.w = f2bf_rne(acc[mi][ni][3] + bnv[ni]);
                *(ushort4*)&VT[((size_t)(bi * 8 + hh) * 64 + dh) * 2048 + s] = pk;
            }
        }
    }
}

// ---------------------------------------------------------------------------
// Kernel 2: flash attention, S^T formulation.
// S^T = K·Q^T (A=K-frag, B=Q-frag) -> D rows=key, cols=q. P^T packed with
// v_cvt_pk_bf16_f32 (RNE, 1 instr per 2 scores) IN REGISTERS before the
// barrier, then ds_write_b64 into Ps[q][key]. Denominator l computed by
// MFMA against a constant ones B-fragment (sums the SAME rounded-bf16 P
// the numerator uses -> consistent, and removes the serial VALU add chain
// + cross-lane shuffles). Key loop split: full tiles carry zero masking
// code; at most one boundary tile per block does the cmp/cndmask.
// V^T (B,H,DH,S) staged to LDS with 2 b128 copies (loads issued early,
// writes after the barrier). ctx written as bf16 hi/lo; hi overwrites Qb.
// ---------------------------------------------------------------------------
__global__ __launch_bounds__(256) void attn_kernel(
    ush* __restrict__ Qb, const ush* __restrict__ Kb,
    const ush* __restrict__ VT, const int* __restrict__ lens,
    ush* __restrict__ ctx_lo)
{
    __shared__ ush Ps[64 * 72];   // [q_local][key], stride 72
    __shared__ ush Vt[4624];      // [dv][key], addr = dv*72 + ((dv>>4)<<3) + key

    const int tid = threadIdx.x;
    const int w = tid >> 6, l = tid & 63;
    const int l15 = l & 15, g = l >> 4;

    const int id = blockIdx.x;
    const int h = id & 7, qt = (id >> 3) & 31, b = id >> 8;
    const int L = lens[b];
    const int q0 = qt << 6;
    const size_t bh = ((size_t)b * 8 + h) * 2048;

    // Q B-fragments (held all kernel)
    const ush* qptr = Qb + (bh + q0 + w * 16 + l15) * 64 + g * 8;
    const bf16x8 qf0 = *(const bf16x8*)(qptr);
    const bf16x8 qf1 = *(const bf16x8*)(qptr + 32);

    const ush* kbase = Kb + (bh + l15) * 64 + g * 8;

    // V^T staging: thread owns dv row, 16-key segment
    const int dv = tid >> 2, seg = (tid & 3) << 4;
    const ush* vbase = VT + ((size_t)(b * 8 + h) * 64 + dv) * 2048 + seg;
    ush* vt_w = &Vt[dv * 72 + ((dv >> 4) << 3) + seg];

    // Ps pointers (this thread)
    ush* psw = &Ps[(w * 16 + l15) * 72 + (g << 2)];        // P^T write slot
    const ush* pp = &Ps[(w * 16 + l15) * 72 + g * 8];      // A-frag read slot

    // constant ones B-fragment for the l-MFMA (bf16 1.0 = 0x3F80)
    bf16x8 ones;
    #pragma unroll
    for (int j = 0; j < 8; ++j) ones[j] = (short)0x3F80;

    f32x4 o[4];
    f32x4 ol = (f32x4)(0.0f);   // ol[r] = sum_k P[q=g*4+r][k]
    #pragma unroll
    for (int i = 0; i < 4; ++i) o[i] = (f32x4)(0.0f);

    auto tile = [&](int k0, bool masked) {
        // V prefetch (early issue; consumed after the barrier)
        const uint4 v0 = *(const uint4*)(vbase + k0);
        const uint4 v1 = *(const uint4*)(vbase + k0 + 8);

        // S^T[key][q]
        f32x4 s[4];
        #pragma unroll
        for (int st = 0; st < 4; ++st) s[st] = (f32x4)(0.0f);
        const ush* kp = kbase + (size_t)k0 * 64;
        #pragma unroll
        for (int st = 0; st < 4; ++st) {
            const bf16x8 kf0 = *(const bf16x8*)(kp + st * 16 * 64);
            const bf16x8 kf1 = *(const bf16x8*)(kp + st * 16 * 64 + 32);
            s[st] = __builtin_amdgcn_mfma_f32_16x16x32_bf16(kf0, qf0, s[st], 0, 0, 0);
            s[st] = __builtin_amdgcn_mfma_f32_16x16x32_bf16(kf1, qf1, s[st], 0, 0, 0);
        }

        // no-max softmax, fully in registers, BEFORE the barrier
        uint2 pk[4];
        #pragma unroll
        for (int st = 0; st < 4; ++st) {
            float p[4];
            #pragma unroll
            for (int r = 0; r < 4; ++r) {
                float e = EXP2F(s[st][r]);
                if (masked) {
                    const int key = k0 + st * 16 + (g << 2) + r;
                    e = (key < L) ? e : 0.0f;
                }
                p[r] = e;
            }
            pk[st].x = cvt_pk_bf16(p[0], p[1]);
            pk[st].y = cvt_pk_bf16(p[2], p[3]);
        }

        __syncthreads();   // previous iteration's Vt/Ps frag reads complete
        *(uint4*)(vt_w) = v0;
        *(uint4*)(vt_w + 8) = v1;
        #pragma unroll
        for (int st = 0; st < 4; ++st)
            *(uint2*)(psw + st * 16) = pk[st];
        __syncthreads();   // Vt + Ps visible

        // O += P @ V ; l += P @ ones
        const bf16x8 pf0 = *(const bf16x8*)(pp);
        const bf16x8 pf1 = *(const bf16x8*)(pp + 32);
        ol = __builtin_amdgcn_mfma_f32_16x16x32_bf16(pf0, ones, ol, 0, 0, 0);
        ol = __builtin_amdgcn_mfma_f32_16x16x32_bf16(pf1, ones, ol, 0, 0, 0);
        #pragma unroll
        for (int st2 = 0; st2 < 4; ++st2) {
            const ush* vp = &Vt[(st2 * 16 + l15) * 72 + (st2 << 3) + g * 8];
            const bf16x8 vf0 = *(const bf16x8*)(vp);
            const bf16x8 vf1 = *(const bf16x8*)(vp + 32);
            o[st2] = __builtin_amdgcn_mfma_f32_16x16x32_bf16(pf0, vf0, o[st2], 0, 0, 0);
            o[st2] = __builtin_amdgcn_mfma_f32_16x16x32_bf16(pf1, vf1, o[st2], 0, 0, 0);
        }
    };

    const int nfull = L >> 6;
    for (int kt = 0; kt < nfull; ++kt) tile(kt << 6, false);
    if (L & 63) tile(nfull << 6, true);

    #pragma unroll
    for (int r = 0; r < 4; ++r) {
        const float inv = 1.0f / ol[r];   // l for q = g*4+r, lane-local
        const size_t row = bh + q0 + w * 16 + (g << 2) + r;
        #pragma unroll
        for (int st2 = 0; st2 < 4; ++st2) {
            const float val = o[st2][r] * inv;
            const ush hi = f2bf_rne(val);
            const ush lo = f2bf_rne(val - bf2f(hi));
            Qb[row * 64 + st2 * 16 + l15] = hi;        // ctx_hi in place
            ctx_lo[row * 64 + st2 * 16 + l15] = lo;
        }
    }
}

// ---------------------------------------------------------------------------
// Kernel 3: out = ctx @ Wo^T + bo, 3-term split bf16 MFMA
// (hi·hi + lo·hi + hi·lo ~ fp32 accuracy). ctx gathered from (B,H,S,DH).
// ---------------------------------------------------------------------------
__global__ __launch_bounds__(256) void out_gemm_kernel(
    const ush* __restrict__ ctx_hi, const ush* __restrict__ ctx_lo,
    const ush* __restrict__ wo_hi, const ush* __restrict__ wo_lo,
    const float* __restrict__ bo, float* __restrict__ out)
{
    __shared__ ush Ah[4096], Al[4096], Bh[4096], Bl[4096];

    const int t = threadIdx.x;
    const int w = t >> 6, l = t & 63;
    const int l15 = l & 15, g = l >> 4;
    const int m0 = blockIdx.x * 128, n0 = blockIdx.y * 128;
    const int wm = (w & 1) << 6, wn = (w >> 1) << 6;

    const int srow = l >> 2;
    const int sg   = (l & 3) ^ ((srow + (srow >> 2)) & 3);
    const int fsw  = (g ^ ((l15 + (l15 >> 2)) & 3)) << 3;
    const int c0   = w * 2;

    f32x4 acc[4][4];
    #pragma unroll
    for (int i = 0; i < 4; ++i)
        #pragma unroll
        for (int j = 0; j < 4; ++j) acc[i][j] = (f32x4)(0.0f);

    for (int kt = 0; kt < 512; kt += 32) {
        __syncthreads();   // previous frag reads complete
        #pragma unroll
        for (int cc = 0; cc < 2; ++cc) {
            const int c = c0 + cc;
            // ctx rows: token m; k = h*64 + dh (BK=32 stays inside one head)
            const int m = m0 + c * 16 + srow;
            const int k = kt + sg * 8;
            const size_t ga = ((size_t)((m >> 11) * 8 + (k >> 6)) * 2048 + (m & (NS - 1))) * 64 + (k & 63);
            GLL16(&ctx_hi[ga], &Ah[c * 512 + l * 8]);
            GLL16(&ctx_lo[ga], &Al[c * 512 + l * 8]);
            const size_t gb = (size_t)(n0 + c * 16 + srow) * 512 + kt + sg * 8;
            GLL16(&wo_hi[gb], &Bh[c * 512 + l * 8]);
            GLL16(&wo_lo[gb], &Bl[c * 512 + l * 8]);
        }
        __syncthreads();   // staged

        bf16x8 ah[4], al[4], bh4[4], bl4[4];
        #pragma unroll
        for (int mi = 0; mi < 4; ++mi) {
            const int off = (((w & 1) << 2) + mi) * 512 + l15 * 32 + fsw;
            ah[mi] = *(const bf16x8*)&Ah[off];
            al[mi] = *(const bf16x8*)&Al[off];
        }
        #pragma unroll
        for (int ni = 0; ni < 4; ++ni) {
            const int off = (((w >> 1) << 2) + ni) * 512 + l15 * 32 + fsw;
            bh4[ni] = *(const bf16x8*)&Bh[off];
            bl4[ni] = *(const bf16x8*)&Bl[off];
        }
        #pragma unroll
        for (int mi = 0; mi < 4; ++mi)
            #pragma unroll
            for (int ni = 0; ni < 4; ++ni) {
                acc[mi][ni] = __builtin_amdgcn_mfma_f32_16x16x32_bf16(ah[mi], bh4[ni], acc[mi][ni], 0, 0, 0);
                acc[mi][ni] = __builtin_amdgcn_mfma_f32_16x16x32_bf16(al[mi], bh4[ni], acc[mi][ni], 0, 0, 0);
                acc[mi][ni] = __builtin_amdgcn_mfma_f32_16x16x32_bf16(ah[mi], bl4[ni], acc[mi][ni], 0, 0, 0);
            }
    }

    float bov[4];
    #pragma unroll
    for (int ni = 0; ni < 4; ++ni) bov[ni] = bo[n0 + wn + ni * 16 + l15];

    #pragma unroll
    for (int mi = 0; mi < 4; ++mi)
        #pragma unroll
        for (int ni = 0; ni < 4; ++ni) {
            const int n = n0 + wn + ni * 16 + l15;
            #pragma unroll
            for (int r = 0; r < 4; ++r) {
                const int m = m0 + wm + mi * 16 + (g << 2) + r;
                out[(size_t)m * 512 + n] = acc[mi][ni][r] + bov[ni];
            }
        }
}

// ---------------------------------------------------------------------------
extern "C" void kernel_launch(void* const* d_in, const int* in_sizes, int n_in,
                              void* d_out, int out_size, void* d_ws, size_t ws_size,
                              hipStream_t stream)
{
    const float* xq   = (const float*)d_in[0];
    const float* xk   = (const float*)d_in[1];
    const float* xv   = (const float*)d_in[2];
    const float* Wq   = (const float*)d_in[3];
    const float* bq   = (const float*)d_in[4];
    const float* Wk   = (const float*)d_in[5];
    const float* bk   = (const float*)d_in[6];
    const float* Wv   = (const float*)d_in[7];
    const float* bv   = (const float*)d_in[8];
    const float* Wo   = (const float*)d_in[9];
    const float* bo   = (const float*)d_in[10];
    const int*   lens = (const int*)d_in[11];
    float* out = (float*)d_out;

    const size_t elems = (size_t)NB * NHH * NS * NDH;   // 8.39M
    ush* Qb     = (ush*)d_ws;          // bf16 Q (pre-scaled); later ctx_hi in place
    ush* Kb     = Qb + elems;
    ush* VT     = Kb + elems;          // V transposed (B,H,DH,S)
    ush* ctx_lo = VT + elems;
    ush* wbf    = ctx_lo + elems;      // Wq,Wk,Wv bf16 (3*262144)
    ush* wo_hi  = wbf + 3 * 262144;
    ush* wo_lo  = wo_hi + 262144;
    // total: 4*8.39M + 5*262144 shorts = 69.7 MB (< 100.7 MB proven in R1)

    const dim3 blk(256);
    conv_w_kernel<<<dim3(256, 4), blk, 0, stream>>>(Wq, Wk, Wv, Wo, wbf, wo_hi, wo_lo);
    qkv_gemm_kernel<<<dim3(128, 4, 3), blk, 0, stream>>>(
        xq, xk, xv, wbf, bq, bk, bv, Qb, Kb, VT);
    attn_kernel<<<dim3(NB * NHH * (NS / 64)), blk, 0, stream>>>(Qb, Kb, VT, lens, ctx_lo);
    out_gemm_kernel<<<dim3(128, 4), blk, 0, stream>>>(Qb, ctx_lo, wo_hi, wo_lo, bo, out);
}